// Round 18
// baseline (134.991 us; speedup 1.0000x reference)
//
#include <hip/hip_runtime.h>
#include <hip/hip_bf16.h>
#include <math.h>

#define Hd   512
#define FPd  256
#define Ed   512
#define NFd  768
#define Ld   512
#define Bd   32
#define K2H  1024            // 2H
#define Nd   1024            // NF + FP
#define Md   (Ld * Bd)       // 16384

typedef _Float16 f16x8  __attribute__((ext_vector_type(8)));
typedef _Float16 f16x4  __attribute__((ext_vector_type(4)));
typedef float    f32x4  __attribute__((ext_vector_type(4)));
typedef float    f32x16 __attribute__((ext_vector_type(16)));

// ---------------------------------------------------------------------------
// Fused prologue (272 blocks x 512 thr):
//  blocks [0,256):   W_big 64x64 tiles + fp16 frag emit.
//    traffic = 2MB*(1024/64 + 1024/64) = 64 MB (half of the 32x32 version).
//    per wave: all lanes share ty -> fs reads broadcast (free); weight
//    loads coalesced (lane = k).
//  blocks [256,272): bias_big[n], 64 n per block, 8 lanes per n.
// Frag layout (matches gemm): fo = ((ntile*64 + t)*64 + lane)*8,
//   n = ntile*32+(lane&31), k = t*16+(lane>>5)*8+j.
// ---------------------------------------------------------------------------
__global__ __launch_bounds__(512)
void prologue(const float* __restrict__ F,
              const float* __restrict__ Wf,
              const float* __restrict__ V,
              const float* __restrict__ Wl,
              const float* __restrict__ bf,
              const float* __restrict__ bl,
              _Float16* __restrict__ Bh,
              float* __restrict__ bias) {
    __shared__ float fs[64][68];       // 272B row stride, 16B-aligned
    __shared__ float wtile[64][68];
    const int bid = blockIdx.x;
    const int tid = threadIdx.x;

    if (bid < 256) {                   // ---- W_big 64x64 + frag emit ----
        const int kx = bid & 15;       // k-tile (64 k)
        const int ny = bid >> 4;       // n-tile (64 n); 768 boundary aligned
        const int n0 = ny * 64;
        const int kl = tid & 63;
        const int k  = kx * 64 + kl;
        const int ty = tid >> 6;       // wave id 0..7 -> rows ty*8..ty*8+7

        const float* src;  const float* wsrc;
        if (n0 < NFd) { src = F + (size_t)n0 * Ed;          wsrc = Wf; }
        else          { src = V + (size_t)(n0 - NFd) * Hd;  wsrc = Wl; }

        float acc[8];
#pragma unroll
        for (int i = 0; i < 8; i++) acc[i] = 0.f;

        for (int e0 = 0; e0 < 512; e0 += 64) {
#pragma unroll
            for (int rep = 0; rep < 2; rep++) {
                int idx = rep * 512 + tid;     // 0..1023 float4 slots
                int i   = idx >> 4;            // row 0..63
                int kq  = idx & 15;            // quad
                float4 v4 = *(const float4*)(src + (size_t)i * 512 + e0 + kq * 4);
                *(float4*)(&fs[i][kq * 4]) = v4;
            }
            __syncthreads();
#pragma unroll 4
            for (int kk = 0; kk < 64; kk += 4) {
                float w0 = wsrc[(size_t)(e0 + kk + 0) * K2H + k];
                float w1 = wsrc[(size_t)(e0 + kk + 1) * K2H + k];
                float w2 = wsrc[(size_t)(e0 + kk + 2) * K2H + k];
                float w3 = wsrc[(size_t)(e0 + kk + 3) * K2H + k];
#pragma unroll
                for (int i = 0; i < 8; i++) {
                    float4 f4 = *(const float4*)(&fs[ty * 8 + i][kk]);
                    acc[i] += f4.x * w0 + f4.y * w1 + f4.z * w2 + f4.w * w3;
                }
            }
            __syncthreads();
        }
        // emit: via LDS tile -> fp16 frags (one 64x64 tile = 512 slots)
#pragma unroll
        for (int i = 0; i < 8; i++) wtile[ty * 8 + i][kl] = acc[i];
        __syncthreads();
        {
            const int lane = tid & 63;
            const int g    = tid >> 6;         // 0..7
            const int nt   = g >> 2;           // 0..1
            const int k16  = g & 3;            // 0..3
            const int nl   = nt * 32 + (lane & 31);
            const int kf   = k16 * 16 + (lane >> 5) * 8;
            float w[8];
            *(float4*)(w)     = *(const float4*)(&wtile[nl][kf]);
            *(float4*)(w + 4) = *(const float4*)(&wtile[nl][kf + 4]);
            f16x8 h;
#pragma unroll
            for (int j = 0; j < 8; j++) h[j] = (_Float16)w[j];
            const size_t fo =
                ((size_t)((ny * 2 + nt) * 64 + (kx * 4 + k16)) * 64 + lane) * 8;
            *(f16x8*)(Bh + fo) = h;
        }
        return;
    }

    {                                  // ---- bias ----
        const int n0 = (bid - 256) * 64;
        const int ng = tid >> 3;       // 0..63
        const int p  = tid & 7;        // 8 lanes per n
        const int n  = n0 + ng;
        const float* row; const float* bsrc;
        if (n < NFd) { row = F + (size_t)n * Ed;          bsrc = bf; }
        else         { row = V + (size_t)(n - NFd) * Hd;  bsrc = bl; }
        float a = 0.f;
#pragma unroll
        for (int i = 0; i < 8; i++) {
            const int idx = i * 64 + p * 8;
            f32x4 r0 = *(const f32x4*)(row + idx);
            f32x4 s0 = *(const f32x4*)(bsrc + idx);
            f32x4 r1 = *(const f32x4*)(row + idx + 4);
            f32x4 s1 = *(const f32x4*)(bsrc + idx + 4);
            a += r0[0]*s0[0] + r0[1]*s0[1] + r0[2]*s0[2] + r0[3]*s0[3]
               + r1[0]*s1[0] + r1[1]*s1[1] + r1[2]*s1[2] + r1[3]*s1[3];
        }
        a += __shfl_xor(a, 1);
        a += __shfl_xor(a, 2);
        a += __shfl_xor(a, 4);
        if (p == 0) bias[n] = a;
    }
}

// ---------------------------------------------------------------------------
// GEMM (fp16 x fp16) + fused softmax + direct transposed store.
// Grid 256 = (b, lc): 64 rows x N=1024. 1024 thr = 16 waves, 4/SIMD.
// Wave wn: 64 rows (2 ms) x 64 cols (2 nt), acc[2][2] = 64 AGPR.
// A: LDS frag-major conflict-free, 1-deep global pf, **NT loads** (enc is
// read-once; keep 2MB Bh resident in per-XCD L2 — stores stay cached,
// R11 showed NT stores regress).
// B: 2-deep register pipeline + setprio(1) around MFMA cluster (R17: −8%).
// ---------------------------------------------------------------------------
__global__ __launch_bounds__(1024)
void gemm_direct(const float* __restrict__ enc,
                 const _Float16* __restrict__ Bh,
                 const float* __restrict__ bias,
                 float* __restrict__ out) {
    __shared__ char AsB[2][8192];      // per buf: single fp16 plane
    __shared__ float red[16][64];
    __shared__ float redc[64];

    const int tid  = threadIdx.x;
    const int lane = tid & 63;
    const int wn   = tid >> 6;         // wave 0..15 -> 64-col block
    const int hf   = lane >> 5;
    const int l31  = lane & 31;
    const int b    = blockIdx.x >> 3;  // 0..31
    const int l0   = (blockIdx.x & 7) * 64;

    // bias folded into accumulator init
    float bv[2];
#pragma unroll
    for (int nt = 0; nt < 2; nt++) bv[nt] = bias[wn * 64 + nt * 32 + l31];
    f32x16 acc[2][2];
#pragma unroll
    for (int ms = 0; ms < 2; ms++)
#pragma unroll
        for (int nt = 0; nt < 2; nt++)
#pragma unroll
            for (int r = 0; r < 16; r++) acc[ms][nt][r] = bv[nt];

    // global staging map: thread -> (row = tid>>4 in 0..63, 4 k at (tid&15)*4)
    const int srow = tid >> 4;
    const int skf  = (tid & 15) * 4;
    const float* gA = enc + ((size_t)(l0 + srow) * Bd + b) * K2H + skf;

    // LDS write target (frag-major): constant per thread
    const int kk_w   = skf >> 4;            // 0..3
    const int lh_w   = (skf & 15) >> 3;     // 0..1
    const int j0_w   = skf & 7;             // 0 or 4
    const int lane_w = lh_w * 32 + (srow & 31);
    const int slot_w = lane_w ^ ((lane_w >> 3) & 7) ^ kk_w;
    const uint32_t wb = (uint32_t)((srow >> 5) * 4096 + kk_w * 1024 + slot_w * 16 + j0_w * 2);

    // LDS read base (frag-major): per kk offset = kk*1024 + (rb16 ^ (kk<<4))
    const uint32_t rb16 = (uint32_t)((lane ^ ((lane >> 3) & 7)) << 4);

    // B fragment base pointers for this wave's two column tiles
    const _Float16* Bp0 = Bh + ((size_t)(wn * 2 + 0) * 4096 + lane) * 8;
    const _Float16* Bp1 = Bh + ((size_t)(wn * 2 + 1) * 4096 + lane) * 8;

#define STAGE_CHUNK(dst, p)                                               \
    {                                                                     \
        f16x4 h_;                                                         \
        _Pragma("unroll")                                                 \
        for (int j = 0; j < 4; j++) h_[j] = (_Float16)((p)[j]);           \
        *(f16x4*)((dst) + wb) = h_;                                       \
    }

    // prologue: stage chunk 0; preload B(t=0) and B(t=1)
    {
        f32x4 p0 = __builtin_nontemporal_load((const f32x4*)gA);
        STAGE_CHUNK(AsB[0], p0)
    }
    f16x8 b_cur0 = *(const f16x8*)(Bp0);
    f16x8 b_cur1 = *(const f16x8*)(Bp1);
    f16x8 b_nx0  = *(const f16x8*)(Bp0 + 512);
    f16x8 b_nx1  = *(const f16x8*)(Bp1 + 512);

    for (int c = 0; c < 16; ++c) {
        __syncthreads();               // buf[c&1] staged; buf[(c+1)&1] free
        f32x4 pfA;
        if (c < 15) pfA = __builtin_nontemporal_load((const f32x4*)(gA + (c + 1) * 64));
        const char* hbase = AsB[c & 1];
#pragma unroll
        for (int kk = 0; kk < 4; ++kk) {
            const uint32_t ko = (uint32_t)(kk * 1024) + (rb16 ^ (uint32_t)(kk << 4));
            f16x8 a0 = *(const f16x8*)(hbase + ko);
            f16x8 a1 = *(const f16x8*)(hbase + 4096 + ko);
            // issue t+2 B loads (2-deep; Bh padded so t+2<=65 is in-bounds)
            const size_t t2 = (size_t)(c * 4 + kk + 2) * 512;
            f16x8 b_n20 = *(const f16x8*)(Bp0 + t2);
            f16x8 b_n21 = *(const f16x8*)(Bp1 + t2);
            __builtin_amdgcn_s_setprio(1);
            acc[0][0] = __builtin_amdgcn_mfma_f32_32x32x16_f16(a0, b_cur0, acc[0][0], 0, 0, 0);
            acc[1][0] = __builtin_amdgcn_mfma_f32_32x32x16_f16(a1, b_cur0, acc[1][0], 0, 0, 0);
            acc[0][1] = __builtin_amdgcn_mfma_f32_32x32x16_f16(a0, b_cur1, acc[0][1], 0, 0, 0);
            acc[1][1] = __builtin_amdgcn_mfma_f32_32x32x16_f16(a1, b_cur1, acc[1][1], 0, 0, 0);
            __builtin_amdgcn_s_setprio(0);
            b_cur0 = b_nx0; b_cur1 = b_nx1;
            b_nx0 = b_n20;  b_nx1 = b_n21;
        }
        if (c < 15) STAGE_CHUNK(AsB[(c + 1) & 1], pfA)
    }

    // ---- epilogue: softmax over N (bias already in acc) + direct store ----
    // C/D layout: col n = lane&31, row rr = (r&3) + 8*(r>>2) + 4*hf
#pragma unroll
    for (int ms = 0; ms < 2; ms++) {
#pragma unroll
        for (int r = 0; r < 16; r++) {
            float mx = fmaxf(acc[ms][0][r], acc[ms][1][r]);
#pragma unroll
            for (int off = 1; off < 32; off <<= 1) mx = fmaxf(mx, __shfl_xor(mx, off));
            if (l31 == r) red[wn][ms * 32 + (r & 3) + 8 * (r >> 2) + 4 * hf] = mx;
        }
    }
    __syncthreads();
    if (tid < 64) {
        float v = red[0][tid];
#pragma unroll
        for (int w = 1; w < 16; w++) v = fmaxf(v, red[w][tid]);
        redc[tid] = v;
    }
    __syncthreads();

#pragma unroll
    for (int ms = 0; ms < 2; ms++) {
#pragma unroll
        for (int r = 0; r < 16; r++) {
            const int rr = ms * 32 + (r & 3) + 8 * (r >> 2) + 4 * hf;
            const float rm = redc[rr];
            float s = 0.f;
#pragma unroll
            for (int nt = 0; nt < 2; nt++) {
                float e = __expf(acc[ms][nt][r] - rm);
                acc[ms][nt][r] = e;
                s += e;
            }
#pragma unroll
            for (int off = 1; off < 32; off <<= 1) s += __shfl_xor(s, off);
            if (l31 == r) red[wn][rr] = s;
        }
    }
    __syncthreads();
    if (tid < 64) {
        float v = 0.f;
#pragma unroll
        for (int w = 0; w < 16; w++) v += red[w][tid];
        redc[tid] = 1.0f / v;
    }
    __syncthreads();

#pragma unroll
    for (int ms = 0; ms < 2; ms++) {
        float invr[16];
#pragma unroll
        for (int r = 0; r < 16; r++)
            invr[r] = redc[ms * 32 + (r & 3) + 8 * (r >> 2) + 4 * hf];
#pragma unroll
        for (int nt = 0; nt < 2; nt++) {
            const int n = wn * 64 + nt * 32 + l31;
            float* op = out + ((size_t)b * Nd + n) * Ld + l0 + ms * 32 + hf * 4;
#pragma unroll
            for (int g = 0; g < 4; g++) {
                float4 v = make_float4(acc[ms][nt][g * 4 + 0] * invr[g * 4 + 0],
                                       acc[ms][nt][g * 4 + 1] * invr[g * 4 + 1],
                                       acc[ms][nt][g * 4 + 2] * invr[g * 4 + 2],
                                       acc[ms][nt][g * 4 + 3] * invr[g * 4 + 3]);
                *(float4*)(op + 8 * g) = v;
            }
        }
    }
}

// ---------------------------------------------------------------------------
// Workspace layout (2.1 MB + pad):
//   bias f32 [1024]        4 KB @ 0x0
//   Bh   f16 [1M + 2K pad] 2 MB + 4 KB @ 0x10000  (pad for 2-deep tail reads)
// ---------------------------------------------------------------------------
extern "C" void kernel_launch(void* const* d_in, const int* in_sizes, int n_in,
                              void* d_out, int out_size, void* d_ws, size_t ws_size,
                              hipStream_t stream) {
    (void)in_sizes; (void)n_in; (void)out_size; (void)ws_size;

    const float* F    = (const float*)d_in[0];   // (768, 512)
    const float* enc  = (const float*)d_in[1];   // (512, 32, 1024)
    const float* Wlin = (const float*)d_in[2];   // (512, 1024)
    const float* blin = (const float*)d_in[3];   // (512,)
    const float* Wfea = (const float*)d_in[4];   // (512, 1024)
    const float* bfea = (const float*)d_in[5];   // (512,)
    const float* V    = (const float*)d_in[6];   // (256, 512)
    float* out = (float*)d_out;                  // (32, 1024, 512)

    char* ws = (char*)d_ws;
    float*    bias = (float*)ws;                  // 4 KB
    _Float16* Bh   = (_Float16*)(ws + 0x10000);   // 2 MB (+4 KB pad)

    prologue<<<dim3(272), 512, 0, stream>>>(F, Wfea, V, Wlin, bfea, blin, Bh, bias);
    gemm_direct<<<dim3(256), 1024, 0, stream>>>(enc, Bh, bias, out);
}

// Round 19
// 114.759 us; speedup vs baseline: 1.1763x; 1.1763x over previous
//
#include <hip/hip_runtime.h>
#include <hip/hip_bf16.h>
#include <math.h>

#define Hd   512
#define FPd  256
#define Ed   512
#define NFd  768
#define Ld   512
#define Bd   32
#define K2H  1024            // 2H
#define Nd   1024            // NF + FP
#define Md   (Ld * Bd)       // 16384

typedef _Float16 f16x8  __attribute__((ext_vector_type(8)));
typedef _Float16 f16x4  __attribute__((ext_vector_type(4)));
typedef float    f32x4  __attribute__((ext_vector_type(4)));
typedef float    f32x16 __attribute__((ext_vector_type(16)));

// ---------------------------------------------------------------------------
// Kernel 1: W_big build + fp16 frag repack (R15-verified config: 32x32
// tiles, 1024 blocks x 256 thr, 4 rows/thread -> 4 blocks/CU, short
// 512-deep chains; measured ~33 us with bias launch).
// Frag layout: fo = ((ntile*64 + t)*64 + lane)*8,
//   n = ntile*32+(lane&31), k = t*16+(lane>>5)*8+j.
// ---------------------------------------------------------------------------
__global__ __launch_bounds__(256)
void build_wpack(const float* __restrict__ F,
                 const float* __restrict__ Wf,
                 const float* __restrict__ V,
                 const float* __restrict__ Wl,
                 _Float16* __restrict__ Bh) {
    __shared__ float fs[32][64];
    __shared__ float wtile[32][36];
    const int tid = threadIdx.x;
    const int kx  = blockIdx.x;         // 0..31
    const int ny  = blockIdx.y;         // 0..31
    const int n0  = ny * 32;
    const int kl  = tid & 31;
    const int k   = kx * 32 + kl;
    const int ty  = tid >> 5;           // 0..7 -> 4 rows each

    const float* src;  const float* wsrc;
    if (n0 < NFd) { src = F + (size_t)n0 * Ed;          wsrc = Wf; }
    else          { src = V + (size_t)(n0 - NFd) * Hd;  wsrc = Wl; }

    float acc[4];
#pragma unroll
    for (int i = 0; i < 4; i++) acc[i] = 0.f;

    for (int e0 = 0; e0 < 512; e0 += 64) {
#pragma unroll
        for (int rep = 0; rep < 2; rep++) {
            int idx = rep * 256 + tid;
            int i   = idx >> 4;
            int kq  = idx & 15;
            float4 v4 = *(const float4*)(src + (size_t)i * 512 + e0 + kq * 4);
            *(float4*)(&fs[i][kq * 4]) = v4;
        }
        __syncthreads();
#pragma unroll 4
        for (int kk = 0; kk < 64; kk += 4) {
            float w0 = wsrc[(size_t)(e0 + kk + 0) * K2H + k];
            float w1 = wsrc[(size_t)(e0 + kk + 1) * K2H + k];
            float w2 = wsrc[(size_t)(e0 + kk + 2) * K2H + k];
            float w3 = wsrc[(size_t)(e0 + kk + 3) * K2H + k];
#pragma unroll
            for (int i = 0; i < 4; i++) {
                float4 f4 = *(const float4*)(&fs[ty * 4 + i][kk]);
                acc[i] += f4.x * w0 + f4.y * w1 + f4.z * w2 + f4.w * w3;
            }
        }
        __syncthreads();
    }
#pragma unroll
    for (int i = 0; i < 4; i++) wtile[ty * 4 + i][kl] = acc[i];
    __syncthreads();
    if (tid < 128) {
        const int lane = tid & 63;
        const int ksl  = tid >> 6;            // 0..1
        const int nl   = lane & 31;
        const int kf   = ksl * 16 + (lane >> 5) * 8;
        float w[8];
        *(float4*)(w)     = *(const float4*)(&wtile[nl][kf]);
        *(float4*)(w + 4) = *(const float4*)(&wtile[nl][kf + 4]);
        f16x8 h;
#pragma unroll
        for (int j = 0; j < 8; j++) h[j] = (_Float16)w[j];
        const size_t fo = ((size_t)((ny * 64) + (kx * 2 + ksl)) * 64 + lane) * 8;
        *(f16x8*)(Bh + fo) = h;
    }
}

// ---------------------------------------------------------------------------
// Kernel 1b: bias_big[n] (R15-verified)
// ---------------------------------------------------------------------------
__global__ __launch_bounds__(64)
void build_bias(const float* __restrict__ F, const float* __restrict__ bf,
                const float* __restrict__ V, const float* __restrict__ bl,
                float* __restrict__ bias) {
    const int n    = blockIdx.x;
    const int lane = threadIdx.x;
    const float* row; const float* bsrc;
    if (n < NFd) { row = F + (size_t)n * Ed;          bsrc = bf; }
    else         { row = V + (size_t)(n - NFd) * Hd;  bsrc = bl; }
    float a = 0.f;
#pragma unroll
    for (int rep = 0; rep < 8; rep++) {
        int e = rep * 64 + lane;
        a += row[e] * bsrc[e];
    }
#pragma unroll
    for (int off = 1; off < 64; off <<= 1) a += __shfl_xor(a, off);
    if (lane == 0) bias[n] = a;
}

// ---------------------------------------------------------------------------
// Kernel 2 (R18-verified, byte-identical): GEMM (fp16 x fp16) + fused
// softmax + direct transposed store. NT loads on enc (read-once stream;
// keeps 2MB Bh L2-resident -> gemm 72 -> ~46 us in R18). 2-deep B register
// pipeline + setprio(1) around MFMA cluster. A: LDS frag-major
// conflict-free (R13: conflicts=0), cached stores.
// ---------------------------------------------------------------------------
__global__ __launch_bounds__(1024)
void gemm_direct(const float* __restrict__ enc,
                 const _Float16* __restrict__ Bh,
                 const float* __restrict__ bias,
                 float* __restrict__ out) {
    __shared__ char AsB[2][8192];      // per buf: single fp16 plane
    __shared__ float red[16][64];
    __shared__ float redc[64];

    const int tid  = threadIdx.x;
    const int lane = tid & 63;
    const int wn   = tid >> 6;         // wave 0..15 -> 64-col block
    const int hf   = lane >> 5;
    const int l31  = lane & 31;
    const int b    = blockIdx.x >> 3;  // 0..31
    const int l0   = (blockIdx.x & 7) * 64;

    // bias folded into accumulator init
    float bv[2];
#pragma unroll
    for (int nt = 0; nt < 2; nt++) bv[nt] = bias[wn * 64 + nt * 32 + l31];
    f32x16 acc[2][2];
#pragma unroll
    for (int ms = 0; ms < 2; ms++)
#pragma unroll
        for (int nt = 0; nt < 2; nt++)
#pragma unroll
            for (int r = 0; r < 16; r++) acc[ms][nt][r] = bv[nt];

    // global staging map: thread -> (row = tid>>4 in 0..63, 4 k at (tid&15)*4)
    const int srow = tid >> 4;
    const int skf  = (tid & 15) * 4;
    const float* gA = enc + ((size_t)(l0 + srow) * Bd + b) * K2H + skf;

    // LDS write target (frag-major): constant per thread
    const int kk_w   = skf >> 4;            // 0..3
    const int lh_w   = (skf & 15) >> 3;     // 0..1
    const int j0_w   = skf & 7;             // 0 or 4
    const int lane_w = lh_w * 32 + (srow & 31);
    const int slot_w = lane_w ^ ((lane_w >> 3) & 7) ^ kk_w;
    const uint32_t wb = (uint32_t)((srow >> 5) * 4096 + kk_w * 1024 + slot_w * 16 + j0_w * 2);

    // LDS read base (frag-major): per kk offset = kk*1024 + (rb16 ^ (kk<<4))
    const uint32_t rb16 = (uint32_t)((lane ^ ((lane >> 3) & 7)) << 4);

    // B fragment base pointers for this wave's two column tiles
    const _Float16* Bp0 = Bh + ((size_t)(wn * 2 + 0) * 4096 + lane) * 8;
    const _Float16* Bp1 = Bh + ((size_t)(wn * 2 + 1) * 4096 + lane) * 8;

#define STAGE_CHUNK(dst, p)                                               \
    {                                                                     \
        f16x4 h_;                                                         \
        _Pragma("unroll")                                                 \
        for (int j = 0; j < 4; j++) h_[j] = (_Float16)((p)[j]);           \
        *(f16x4*)((dst) + wb) = h_;                                       \
    }

    // prologue: stage chunk 0; preload B(t=0) and B(t=1)
    {
        f32x4 p0 = __builtin_nontemporal_load((const f32x4*)gA);
        STAGE_CHUNK(AsB[0], p0)
    }
    f16x8 b_cur0 = *(const f16x8*)(Bp0);
    f16x8 b_cur1 = *(const f16x8*)(Bp1);
    f16x8 b_nx0  = *(const f16x8*)(Bp0 + 512);
    f16x8 b_nx1  = *(const f16x8*)(Bp1 + 512);

    for (int c = 0; c < 16; ++c) {
        __syncthreads();               // buf[c&1] staged; buf[(c+1)&1] free
        f32x4 pfA;
        if (c < 15) pfA = __builtin_nontemporal_load((const f32x4*)(gA + (c + 1) * 64));
        const char* hbase = AsB[c & 1];
#pragma unroll
        for (int kk = 0; kk < 4; ++kk) {
            const uint32_t ko = (uint32_t)(kk * 1024) + (rb16 ^ (uint32_t)(kk << 4));
            f16x8 a0 = *(const f16x8*)(hbase + ko);
            f16x8 a1 = *(const f16x8*)(hbase + 4096 + ko);
            // issue t+2 B loads (2-deep; Bh padded so t+2<=65 is in-bounds)
            const size_t t2 = (size_t)(c * 4 + kk + 2) * 512;
            f16x8 b_n20 = *(const f16x8*)(Bp0 + t2);
            f16x8 b_n21 = *(const f16x8*)(Bp1 + t2);
            __builtin_amdgcn_s_setprio(1);
            acc[0][0] = __builtin_amdgcn_mfma_f32_32x32x16_f16(a0, b_cur0, acc[0][0], 0, 0, 0);
            acc[1][0] = __builtin_amdgcn_mfma_f32_32x32x16_f16(a1, b_cur0, acc[1][0], 0, 0, 0);
            acc[0][1] = __builtin_amdgcn_mfma_f32_32x32x16_f16(a0, b_cur1, acc[0][1], 0, 0, 0);
            acc[1][1] = __builtin_amdgcn_mfma_f32_32x32x16_f16(a1, b_cur1, acc[1][1], 0, 0, 0);
            __builtin_amdgcn_s_setprio(0);
            b_cur0 = b_nx0; b_cur1 = b_nx1;
            b_nx0 = b_n20;  b_nx1 = b_n21;
        }
        if (c < 15) STAGE_CHUNK(AsB[(c + 1) & 1], pfA)
    }

    // ---- epilogue: softmax over N (bias already in acc) + direct store ----
    // C/D layout: col n = lane&31, row rr = (r&3) + 8*(r>>2) + 4*hf
#pragma unroll
    for (int ms = 0; ms < 2; ms++) {
#pragma unroll
        for (int r = 0; r < 16; r++) {
            float mx = fmaxf(acc[ms][0][r], acc[ms][1][r]);
#pragma unroll
            for (int off = 1; off < 32; off <<= 1) mx = fmaxf(mx, __shfl_xor(mx, off));
            if (l31 == r) red[wn][ms * 32 + (r & 3) + 8 * (r >> 2) + 4 * hf] = mx;
        }
    }
    __syncthreads();
    if (tid < 64) {
        float v = red[0][tid];
#pragma unroll
        for (int w = 1; w < 16; w++) v = fmaxf(v, red[w][tid]);
        redc[tid] = v;
    }
    __syncthreads();

#pragma unroll
    for (int ms = 0; ms < 2; ms++) {
#pragma unroll
        for (int r = 0; r < 16; r++) {
            const int rr = ms * 32 + (r & 3) + 8 * (r >> 2) + 4 * hf;
            const float rm = redc[rr];
            float s = 0.f;
#pragma unroll
            for (int nt = 0; nt < 2; nt++) {
                float e = __expf(acc[ms][nt][r] - rm);
                acc[ms][nt][r] = e;
                s += e;
            }
#pragma unroll
            for (int off = 1; off < 32; off <<= 1) s += __shfl_xor(s, off);
            if (l31 == r) red[wn][rr] = s;
        }
    }
    __syncthreads();
    if (tid < 64) {
        float v = 0.f;
#pragma unroll
        for (int w = 0; w < 16; w++) v += red[w][tid];
        redc[tid] = 1.0f / v;
    }
    __syncthreads();

#pragma unroll
    for (int ms = 0; ms < 2; ms++) {
        float invr[16];
#pragma unroll
        for (int r = 0; r < 16; r++)
            invr[r] = redc[ms * 32 + (r & 3) + 8 * (r >> 2) + 4 * hf];
#pragma unroll
        for (int nt = 0; nt < 2; nt++) {
            const int n = wn * 64 + nt * 32 + l31;
            float* op = out + ((size_t)b * Nd + n) * Ld + l0 + ms * 32 + hf * 4;
#pragma unroll
            for (int g = 0; g < 4; g++) {
                float4 v = make_float4(acc[ms][nt][g * 4 + 0] * invr[g * 4 + 0],
                                       acc[ms][nt][g * 4 + 1] * invr[g * 4 + 1],
                                       acc[ms][nt][g * 4 + 2] * invr[g * 4 + 2],
                                       acc[ms][nt][g * 4 + 3] * invr[g * 4 + 3]);
                *(float4*)(op + 8 * g) = v;
            }
        }
    }
}

// ---------------------------------------------------------------------------
// Workspace layout (2.1 MB + pad):
//   bias f32 [1024]        4 KB @ 0x0
//   Bh   f16 [1M + 2K pad] 2 MB + 4 KB @ 0x10000  (pad for 2-deep tail reads)
// ---------------------------------------------------------------------------
extern "C" void kernel_launch(void* const* d_in, const int* in_sizes, int n_in,
                              void* d_out, int out_size, void* d_ws, size_t ws_size,
                              hipStream_t stream) {
    (void)in_sizes; (void)n_in; (void)out_size; (void)ws_size;

    const float* F    = (const float*)d_in[0];   // (768, 512)
    const float* enc  = (const float*)d_in[1];   // (512, 32, 1024)
    const float* Wlin = (const float*)d_in[2];   // (512, 1024)
    const float* blin = (const float*)d_in[3];   // (512,)
    const float* Wfea = (const float*)d_in[4];   // (512, 1024)
    const float* bfea = (const float*)d_in[5];   // (512,)
    const float* V    = (const float*)d_in[6];   // (256, 512)
    float* out = (float*)d_out;                  // (32, 1024, 512)

    char* ws = (char*)d_ws;
    float*    bias = (float*)ws;                  // 4 KB
    _Float16* Bh   = (_Float16*)(ws + 0x10000);   // 2 MB (+4 KB pad)

    build_wpack<<<dim3(32, 32), 256, 0, stream>>>(F, Wfea, V, Wlin, Bh);
    build_bias<<<dim3(1024), 64, 0, stream>>>(F, bfea, V, blin, bias);
    gemm_direct<<<dim3(256), 1024, 0, stream>>>(enc, Bh, bias, out);
}

// Round 20
// 112.581 us; speedup vs baseline: 1.1991x; 1.0193x over previous
//
#include <hip/hip_runtime.h>
#include <hip/hip_bf16.h>
#include <math.h>

#define Hd   512
#define FPd  256
#define Ed   512
#define NFd  768
#define Ld   512
#define Bd   32
#define K2H  1024            // 2H
#define Nd   1024            // NF + FP
#define Md   (Ld * Bd)       // 16384

typedef _Float16 f16x8  __attribute__((ext_vector_type(8)));
typedef _Float16 f16x4  __attribute__((ext_vector_type(4)));
typedef float    f32x4  __attribute__((ext_vector_type(4)));
typedef float    f32x16 __attribute__((ext_vector_type(16)));

// ---------------------------------------------------------------------------
// Kernel 1: W_big build + fp16 frag repack.
// R20 change: weight panel STAGED THROUGH LDS (ws[64][32] per 64-e chunk,
// coalesced) — inner loop is pure LDS+VALU, no strided global loads in the
// FMA chain (R19: 512 serial 4KB-stride scalar globals/thread = the ~35us).
// Frag layout: fo = ((ntile*64 + t)*64 + lane)*8,
//   n = ntile*32+(lane&31), k = t*16+(lane>>5)*8+j.
// grid (32,32), 256 thr, 4 rows/thread, ~22.5KB LDS -> 4+ blocks/CU.
// ---------------------------------------------------------------------------
__global__ __launch_bounds__(256)
void build_wpack(const float* __restrict__ F,
                 const float* __restrict__ Wf,
                 const float* __restrict__ V,
                 const float* __restrict__ Wl,
                 _Float16* __restrict__ Bh) {
    __shared__ float fs[32][68];       // [n-local][e-local], pad 68
    __shared__ float ws[64][36];       // [e-local][k-local], pad 36
    __shared__ float wtile[32][36];
    const int tid = threadIdx.x;
    const int kx  = blockIdx.x;         // 0..31
    const int ny  = blockIdx.y;         // 0..31
    const int n0  = ny * 32;
    const int kl  = tid & 31;
    const int ty  = tid >> 5;           // 0..7 -> 4 rows each

    const float* src;  const float* wsrc;
    if (n0 < NFd) { src = F + (size_t)n0 * Ed;          wsrc = Wf; }
    else          { src = V + (size_t)(n0 - NFd) * Hd;  wsrc = Wl; }
    const float* wbase = wsrc + kx * 32;

    float acc[4];
#pragma unroll
    for (int i = 0; i < 4; i++) acc[i] = 0.f;

    for (int e0 = 0; e0 < 512; e0 += 64) {
        // stage fs: 32 rows x 64 e = 512 float4 slots
#pragma unroll
        for (int rep = 0; rep < 2; rep++) {
            int idx = rep * 256 + tid;
            int i   = idx >> 4;
            int q   = idx & 15;
            float4 v4 = *(const float4*)(src + (size_t)i * 512 + e0 + q * 4);
            *(float4*)(&fs[i][q * 4]) = v4;
        }
        // stage ws: 64 e x 32 k = 512 float4 slots (8 lanes per e-row)
#pragma unroll
        for (int rep = 0; rep < 2; rep++) {
            int idx = rep * 256 + tid;
            int e   = idx >> 3;
            int q   = idx & 7;
            float4 v4 = *(const float4*)(wbase + (size_t)(e0 + e) * K2H + q * 4);
            *(float4*)(&ws[e][q * 4]) = v4;
        }
        __syncthreads();
#pragma unroll 4
        for (int kk = 0; kk < 64; kk += 4) {
            float w0 = ws[kk + 0][kl];
            float w1 = ws[kk + 1][kl];
            float w2 = ws[kk + 2][kl];
            float w3 = ws[kk + 3][kl];
#pragma unroll
            for (int i = 0; i < 4; i++) {
                float4 f4 = *(const float4*)(&fs[ty * 4 + i][kk]);
                acc[i] += f4.x * w0 + f4.y * w1 + f4.z * w2 + f4.w * w3;
            }
        }
        __syncthreads();
    }
#pragma unroll
    for (int i = 0; i < 4; i++) wtile[ty * 4 + i][kl] = acc[i];
    __syncthreads();
    if (tid < 128) {
        const int lane = tid & 63;
        const int ksl  = tid >> 6;            // 0..1
        const int nl   = lane & 31;
        const int kf   = ksl * 16 + (lane >> 5) * 8;
        float w[8];
        *(float4*)(w)     = *(const float4*)(&wtile[nl][kf]);
        *(float4*)(w + 4) = *(const float4*)(&wtile[nl][kf + 4]);
        f16x8 h;
#pragma unroll
        for (int j = 0; j < 8; j++) h[j] = (_Float16)w[j];
        const size_t fo = ((size_t)((ny * 64) + (kx * 2 + ksl)) * 64 + lane) * 8;
        *(f16x8*)(Bh + fo) = h;
    }
}

// ---------------------------------------------------------------------------
// Kernel 1b: bias_big[n] (R15-verified)
// ---------------------------------------------------------------------------
__global__ __launch_bounds__(64)
void build_bias(const float* __restrict__ F, const float* __restrict__ bf,
                const float* __restrict__ V, const float* __restrict__ bl,
                float* __restrict__ bias) {
    const int n    = blockIdx.x;
    const int lane = threadIdx.x;
    const float* row; const float* bsrc;
    if (n < NFd) { row = F + (size_t)n * Ed;          bsrc = bf; }
    else         { row = V + (size_t)(n - NFd) * Hd;  bsrc = bl; }
    float a = 0.f;
#pragma unroll
    for (int rep = 0; rep < 8; rep++) {
        int e = rep * 64 + lane;
        a += row[e] * bsrc[e];
    }
#pragma unroll
    for (int off = 1; off < 64; off <<= 1) a += __shfl_xor(a, off);
    if (lane == 0) bias[n] = a;
}

// ---------------------------------------------------------------------------
// Kernel 2 (R19 byte-identical): GEMM (fp16 x fp16) + fused softmax +
// direct transposed store. NT enc loads, 2-deep B register pipeline,
// setprio(1) around MFMA cluster, LDS frag-major conflict-free A.
// ---------------------------------------------------------------------------
__global__ __launch_bounds__(1024)
void gemm_direct(const float* __restrict__ enc,
                 const _Float16* __restrict__ Bh,
                 const float* __restrict__ bias,
                 float* __restrict__ out) {
    __shared__ char AsB[2][8192];      // per buf: single fp16 plane
    __shared__ float red[16][64];
    __shared__ float redc[64];

    const int tid  = threadIdx.x;
    const int lane = tid & 63;
    const int wn   = tid >> 6;         // wave 0..15 -> 64-col block
    const int hf   = lane >> 5;
    const int l31  = lane & 31;
    const int b    = blockIdx.x >> 3;  // 0..31
    const int l0   = (blockIdx.x & 7) * 64;

    // bias folded into accumulator init
    float bv[2];
#pragma unroll
    for (int nt = 0; nt < 2; nt++) bv[nt] = bias[wn * 64 + nt * 32 + l31];
    f32x16 acc[2][2];
#pragma unroll
    for (int ms = 0; ms < 2; ms++)
#pragma unroll
        for (int nt = 0; nt < 2; nt++)
#pragma unroll
            for (int r = 0; r < 16; r++) acc[ms][nt][r] = bv[nt];

    // global staging map: thread -> (row = tid>>4 in 0..63, 4 k at (tid&15)*4)
    const int srow = tid >> 4;
    const int skf  = (tid & 15) * 4;
    const float* gA = enc + ((size_t)(l0 + srow) * Bd + b) * K2H + skf;

    // LDS write target (frag-major): constant per thread
    const int kk_w   = skf >> 4;            // 0..3
    const int lh_w   = (skf & 15) >> 3;     // 0..1
    const int j0_w   = skf & 7;             // 0 or 4
    const int lane_w = lh_w * 32 + (srow & 31);
    const int slot_w = lane_w ^ ((lane_w >> 3) & 7) ^ kk_w;
    const uint32_t wb = (uint32_t)((srow >> 5) * 4096 + kk_w * 1024 + slot_w * 16 + j0_w * 2);

    // LDS read base (frag-major): per kk offset = kk*1024 + (rb16 ^ (kk<<4))
    const uint32_t rb16 = (uint32_t)((lane ^ ((lane >> 3) & 7)) << 4);

    // B fragment base pointers for this wave's two column tiles
    const _Float16* Bp0 = Bh + ((size_t)(wn * 2 + 0) * 4096 + lane) * 8;
    const _Float16* Bp1 = Bh + ((size_t)(wn * 2 + 1) * 4096 + lane) * 8;

#define STAGE_CHUNK(dst, p)                                               \
    {                                                                     \
        f16x4 h_;                                                         \
        _Pragma("unroll")                                                 \
        for (int j = 0; j < 4; j++) h_[j] = (_Float16)((p)[j]);           \
        *(f16x4*)((dst) + wb) = h_;                                       \
    }

    // prologue: stage chunk 0; preload B(t=0) and B(t=1)
    {
        f32x4 p0 = __builtin_nontemporal_load((const f32x4*)gA);
        STAGE_CHUNK(AsB[0], p0)
    }
    f16x8 b_cur0 = *(const f16x8*)(Bp0);
    f16x8 b_cur1 = *(const f16x8*)(Bp1);
    f16x8 b_nx0  = *(const f16x8*)(Bp0 + 512);
    f16x8 b_nx1  = *(const f16x8*)(Bp1 + 512);

    for (int c = 0; c < 16; ++c) {
        __syncthreads();               // buf[c&1] staged; buf[(c+1)&1] free
        f32x4 pfA;
        if (c < 15) pfA = __builtin_nontemporal_load((const f32x4*)(gA + (c + 1) * 64));
        const char* hbase = AsB[c & 1];
#pragma unroll
        for (int kk = 0; kk < 4; ++kk) {
            const uint32_t ko = (uint32_t)(kk * 1024) + (rb16 ^ (uint32_t)(kk << 4));
            f16x8 a0 = *(const f16x8*)(hbase + ko);
            f16x8 a1 = *(const f16x8*)(hbase + 4096 + ko);
            // issue t+2 B loads (2-deep; Bh padded so t+2<=65 is in-bounds)
            const size_t t2 = (size_t)(c * 4 + kk + 2) * 512;
            f16x8 b_n20 = *(const f16x8*)(Bp0 + t2);
            f16x8 b_n21 = *(const f16x8*)(Bp1 + t2);
            __builtin_amdgcn_s_setprio(1);
            acc[0][0] = __builtin_amdgcn_mfma_f32_32x32x16_f16(a0, b_cur0, acc[0][0], 0, 0, 0);
            acc[1][0] = __builtin_amdgcn_mfma_f32_32x32x16_f16(a1, b_cur0, acc[1][0], 0, 0, 0);
            acc[0][1] = __builtin_amdgcn_mfma_f32_32x32x16_f16(a0, b_cur1, acc[0][1], 0, 0, 0);
            acc[1][1] = __builtin_amdgcn_mfma_f32_32x32x16_f16(a1, b_cur1, acc[1][1], 0, 0, 0);
            __builtin_amdgcn_s_setprio(0);
            b_cur0 = b_nx0; b_cur1 = b_nx1;
            b_nx0 = b_n20;  b_nx1 = b_n21;
        }
        if (c < 15) STAGE_CHUNK(AsB[(c + 1) & 1], pfA)
    }

    // ---- epilogue: softmax over N (bias already in acc) + direct store ----
    // C/D layout: col n = lane&31, row rr = (r&3) + 8*(r>>2) + 4*hf
#pragma unroll
    for (int ms = 0; ms < 2; ms++) {
#pragma unroll
        for (int r = 0; r < 16; r++) {
            float mx = fmaxf(acc[ms][0][r], acc[ms][1][r]);
#pragma unroll
            for (int off = 1; off < 32; off <<= 1) mx = fmaxf(mx, __shfl_xor(mx, off));
            if (l31 == r) red[wn][ms * 32 + (r & 3) + 8 * (r >> 2) + 4 * hf] = mx;
        }
    }
    __syncthreads();
    if (tid < 64) {
        float v = red[0][tid];
#pragma unroll
        for (int w = 1; w < 16; w++) v = fmaxf(v, red[w][tid]);
        redc[tid] = v;
    }
    __syncthreads();

#pragma unroll
    for (int ms = 0; ms < 2; ms++) {
#pragma unroll
        for (int r = 0; r < 16; r++) {
            const int rr = ms * 32 + (r & 3) + 8 * (r >> 2) + 4 * hf;
            const float rm = redc[rr];
            float s = 0.f;
#pragma unroll
            for (int nt = 0; nt < 2; nt++) {
                float e = __expf(acc[ms][nt][r] - rm);
                acc[ms][nt][r] = e;
                s += e;
            }
#pragma unroll
            for (int off = 1; off < 32; off <<= 1) s += __shfl_xor(s, off);
            if (l31 == r) red[wn][rr] = s;
        }
    }
    __syncthreads();
    if (tid < 64) {
        float v = 0.f;
#pragma unroll
        for (int w = 0; w < 16; w++) v += red[w][tid];
        redc[tid] = 1.0f / v;
    }
    __syncthreads();

#pragma unroll
    for (int ms = 0; ms < 2; ms++) {
        float invr[16];
#pragma unroll
        for (int r = 0; r < 16; r++)
            invr[r] = redc[ms * 32 + (r & 3) + 8 * (r >> 2) + 4 * hf];
#pragma unroll
        for (int nt = 0; nt < 2; nt++) {
            const int n = wn * 64 + nt * 32 + l31;
            float* op = out + ((size_t)b * Nd + n) * Ld + l0 + ms * 32 + hf * 4;
#pragma unroll
            for (int g = 0; g < 4; g++) {
                float4 v = make_float4(acc[ms][nt][g * 4 + 0] * invr[g * 4 + 0],
                                       acc[ms][nt][g * 4 + 1] * invr[g * 4 + 1],
                                       acc[ms][nt][g * 4 + 2] * invr[g * 4 + 2],
                                       acc[ms][nt][g * 4 + 3] * invr[g * 4 + 3]);
                *(float4*)(op + 8 * g) = v;
            }
        }
    }
}

// ---------------------------------------------------------------------------
// Workspace layout (2.1 MB + pad):
//   bias f32 [1024]        4 KB @ 0x0
//   Bh   f16 [1M + 2K pad] 2 MB + 4 KB @ 0x10000  (pad for 2-deep tail reads)
// ---------------------------------------------------------------------------
extern "C" void kernel_launch(void* const* d_in, const int* in_sizes, int n_in,
                              void* d_out, int out_size, void* d_ws, size_t ws_size,
                              hipStream_t stream) {
    (void)in_sizes; (void)n_in; (void)out_size; (void)ws_size;

    const float* F    = (const float*)d_in[0];   // (768, 512)
    const float* enc  = (const float*)d_in[1];   // (512, 32, 1024)
    const float* Wlin = (const float*)d_in[2];   // (512, 1024)
    const float* blin = (const float*)d_in[3];   // (512,)
    const float* Wfea = (const float*)d_in[4];   // (512, 1024)
    const float* bfea = (const float*)d_in[5];   // (512,)
    const float* V    = (const float*)d_in[6];   // (256, 512)
    float* out = (float*)d_out;                  // (32, 1024, 512)

    char* ws = (char*)d_ws;
    float*    bias = (float*)ws;                  // 4 KB
    _Float16* Bh   = (_Float16*)(ws + 0x10000);   // 2 MB (+4 KB pad)

    build_wpack<<<dim3(32, 32), 256, 0, stream>>>(F, Wfea, V, Wlin, Bh);
    build_bias<<<dim3(1024), 64, 0, stream>>>(F, bfea, V, blin, bias);
    gemm_direct<<<dim3(256), 1024, 0, stream>>>(enc, Bh, bias, out);
}

// Round 21
// 112.492 us; speedup vs baseline: 1.2000x; 1.0008x over previous
//
#include <hip/hip_runtime.h>
#include <hip/hip_bf16.h>
#include <math.h>

#define Hd   512
#define FPd  256
#define Ed   512
#define NFd  768
#define Ld   512
#define Bd   32
#define K2H  1024            // 2H
#define Nd   1024            // NF + FP
#define Md   (Ld * Bd)       // 16384

typedef _Float16 f16x8  __attribute__((ext_vector_type(8)));
typedef _Float16 f16x4  __attribute__((ext_vector_type(4)));
typedef float    f32x4  __attribute__((ext_vector_type(4)));
typedef float    f32x16 __attribute__((ext_vector_type(16)));

// ---------------------------------------------------------------------------
// Kernel 1: W_big build + fp16 frag repack (R20: weight panel LDS-staged).
// Frag layout: fo = ((ntile*64 + t)*64 + lane)*8,
//   n = ntile*32+(lane&31), k = t*16+(lane>>5)*8+j.
// ---------------------------------------------------------------------------
__global__ __launch_bounds__(256)
void build_wpack(const float* __restrict__ F,
                 const float* __restrict__ Wf,
                 const float* __restrict__ V,
                 const float* __restrict__ Wl,
                 _Float16* __restrict__ Bh) {
    __shared__ float fs[32][68];
    __shared__ float ws[64][36];
    __shared__ float wtile[32][36];
    const int tid = threadIdx.x;
    const int kx  = blockIdx.x;         // 0..31
    const int ny  = blockIdx.y;         // 0..31
    const int n0  = ny * 32;
    const int kl  = tid & 31;
    const int ty  = tid >> 5;           // 0..7 -> 4 rows each

    const float* src;  const float* wsrc;
    if (n0 < NFd) { src = F + (size_t)n0 * Ed;          wsrc = Wf; }
    else          { src = V + (size_t)(n0 - NFd) * Hd;  wsrc = Wl; }
    const float* wbase = wsrc + kx * 32;

    float acc[4];
#pragma unroll
    for (int i = 0; i < 4; i++) acc[i] = 0.f;

    for (int e0 = 0; e0 < 512; e0 += 64) {
#pragma unroll
        for (int rep = 0; rep < 2; rep++) {
            int idx = rep * 256 + tid;
            int i   = idx >> 4;
            int q   = idx & 15;
            float4 v4 = *(const float4*)(src + (size_t)i * 512 + e0 + q * 4);
            *(float4*)(&fs[i][q * 4]) = v4;
        }
#pragma unroll
        for (int rep = 0; rep < 2; rep++) {
            int idx = rep * 256 + tid;
            int e   = idx >> 3;
            int q   = idx & 7;
            float4 v4 = *(const float4*)(wbase + (size_t)(e0 + e) * K2H + q * 4);
            *(float4*)(&ws[e][q * 4]) = v4;
        }
        __syncthreads();
#pragma unroll 4
        for (int kk = 0; kk < 64; kk += 4) {
            float w0 = ws[kk + 0][kl];
            float w1 = ws[kk + 1][kl];
            float w2 = ws[kk + 2][kl];
            float w3 = ws[kk + 3][kl];
#pragma unroll
            for (int i = 0; i < 4; i++) {
                float4 f4 = *(const float4*)(&fs[ty * 4 + i][kk]);
                acc[i] += f4.x * w0 + f4.y * w1 + f4.z * w2 + f4.w * w3;
            }
        }
        __syncthreads();
    }
#pragma unroll
    for (int i = 0; i < 4; i++) wtile[ty * 4 + i][kl] = acc[i];
    __syncthreads();
    if (tid < 128) {
        const int lane = tid & 63;
        const int ksl  = tid >> 6;            // 0..1
        const int nl   = lane & 31;
        const int kf   = ksl * 16 + (lane >> 5) * 8;
        float w[8];
        *(float4*)(w)     = *(const float4*)(&wtile[nl][kf]);
        *(float4*)(w + 4) = *(const float4*)(&wtile[nl][kf + 4]);
        f16x8 h;
#pragma unroll
        for (int j = 0; j < 8; j++) h[j] = (_Float16)w[j];
        const size_t fo = ((size_t)((ny * 64) + (kx * 2 + ksl)) * 64 + lane) * 8;
        *(f16x8*)(Bh + fo) = h;
    }
}

// ---------------------------------------------------------------------------
// Kernel 1b: bias_big[n]
// ---------------------------------------------------------------------------
__global__ __launch_bounds__(64)
void build_bias(const float* __restrict__ F, const float* __restrict__ bf,
                const float* __restrict__ V, const float* __restrict__ bl,
                float* __restrict__ bias) {
    const int n    = blockIdx.x;
    const int lane = threadIdx.x;
    const float* row; const float* bsrc;
    if (n < NFd) { row = F + (size_t)n * Ed;          bsrc = bf; }
    else         { row = V + (size_t)(n - NFd) * Hd;  bsrc = bl; }
    float a = 0.f;
#pragma unroll
    for (int rep = 0; rep < 8; rep++) {
        int e = rep * 64 + lane;
        a += row[e] * bsrc[e];
    }
#pragma unroll
    for (int off = 1; off < 64; off <<= 1) a += __shfl_xor(a, off);
    if (lane == 0) bias[n] = a;
}

// ---------------------------------------------------------------------------
// Kernel 2: GEMM (fp16 x fp16) + fused softmax + direct transposed store.
// R21 change: BK=128 -> 8 chunks, 8 barriers (was 16). Per chunk per
// thread: 2 NT f32x4 loads + 1 ds_write_b128; per kk (8/chunk): 2 ds_read,
// 2 B loads (2-deep pipelined), 4 MFMAs + setprio. Frag-major LDS
// (plane = ms*8KB + kk*1KB + slot*16, slot = f(lane)^kk, f(x)=x^((x>>3)&7))
// — reads permutation-conflict-free, writes 4-lanes/bank-group (b128 min).
// ---------------------------------------------------------------------------
__global__ __launch_bounds__(1024)
void gemm_direct(const float* __restrict__ enc,
                 const _Float16* __restrict__ Bh,
                 const float* __restrict__ bias,
                 float* __restrict__ out) {
    __shared__ char AsB[2][16384];     // per buf: [ms:2][kk:8][slot:64]*16B
    __shared__ float red[16][64];
    __shared__ float redc[64];

    const int tid  = threadIdx.x;
    const int lane = tid & 63;
    const int wn   = tid >> 6;         // wave 0..15 -> 64-col block
    const int hf   = lane >> 5;
    const int l31  = lane & 31;
    const int b    = blockIdx.x >> 3;  // 0..31
    const int l0   = (blockIdx.x & 7) * 64;

    // bias folded into accumulator init
    float bv[2];
#pragma unroll
    for (int nt = 0; nt < 2; nt++) bv[nt] = bias[wn * 64 + nt * 32 + l31];
    f32x16 acc[2][2];
#pragma unroll
    for (int ms = 0; ms < 2; ms++)
#pragma unroll
        for (int nt = 0; nt < 2; nt++)
#pragma unroll
            for (int r = 0; r < 16; r++) acc[ms][nt][r] = bv[nt];

    // staging map: thread -> (row = tid>>4 in 0..63, 8 k at (tid&15)*8)
    const int srow = tid >> 4;
    const int skf  = (tid & 15) * 8;
    const float* gA = enc + ((size_t)(l0 + srow) * Bd + b) * K2H + skf;

    // LDS write target (frag-major BK=128): one b128 per thread per chunk
    const int kk_w   = skf >> 4;            // 0..7
    const int hf_w   = (skf >> 3) & 1;      // 0..1
    const int lane_w = hf_w * 32 + (srow & 31);
    const int slot_w = (lane_w ^ ((lane_w >> 3) & 7)) ^ kk_w;
    const uint32_t wb = (uint32_t)((srow >> 5) * 8192 + kk_w * 1024 + slot_w * 16);

    // LDS read base: per kk offset = kk*1024 + ((f(lane)^kk)<<4)
    const uint32_t rb16 = (uint32_t)((lane ^ ((lane >> 3) & 7)) << 4);

    // B fragment base pointers for this wave's two column tiles
    const _Float16* Bp0 = Bh + ((size_t)(wn * 2 + 0) * 4096 + lane) * 8;
    const _Float16* Bp1 = Bh + ((size_t)(wn * 2 + 1) * 4096 + lane) * 8;

#define STAGE_CHUNK(dst, p0, p1)                                          \
    {                                                                     \
        f16x8 h_;                                                         \
        h_[0] = (_Float16)(p0)[0]; h_[1] = (_Float16)(p0)[1];             \
        h_[2] = (_Float16)(p0)[2]; h_[3] = (_Float16)(p0)[3];             \
        h_[4] = (_Float16)(p1)[0]; h_[5] = (_Float16)(p1)[1];             \
        h_[6] = (_Float16)(p1)[2]; h_[7] = (_Float16)(p1)[3];             \
        *(f16x8*)((dst) + wb) = h_;                                       \
    }

    // prologue: stage chunk 0; preload B(t=0) and B(t=1)
    {
        f32x4 q0 = __builtin_nontemporal_load((const f32x4*)gA);
        f32x4 q1 = __builtin_nontemporal_load((const f32x4*)(gA + 4));
        STAGE_CHUNK(AsB[0], q0, q1)
    }
    f16x8 b_cur0 = *(const f16x8*)(Bp0);
    f16x8 b_cur1 = *(const f16x8*)(Bp1);
    f16x8 b_nx0  = *(const f16x8*)(Bp0 + 512);
    f16x8 b_nx1  = *(const f16x8*)(Bp1 + 512);

    for (int c = 0; c < 8; ++c) {
        __syncthreads();               // buf[c&1] staged; buf[(c+1)&1] free
        f32x4 p0, p1;
        if (c < 7) {
            const float* g = gA + (c + 1) * 128;
            p0 = __builtin_nontemporal_load((const f32x4*)g);
            p1 = __builtin_nontemporal_load((const f32x4*)(g + 4));
        }
        const char* hbase = AsB[c & 1];
#pragma unroll
        for (int kk = 0; kk < 8; ++kk) {
            const uint32_t ko = (uint32_t)(kk * 1024) + (rb16 ^ (uint32_t)(kk << 4));
            f16x8 a0 = *(const f16x8*)(hbase + ko);
            f16x8 a1 = *(const f16x8*)(hbase + 8192 + ko);
            // issue t+2 B loads (2-deep; Bh padded so t+2<=65 is in-bounds)
            const size_t t2 = (size_t)(c * 8 + kk + 2) * 512;
            f16x8 b_n20 = *(const f16x8*)(Bp0 + t2);
            f16x8 b_n21 = *(const f16x8*)(Bp1 + t2);
            __builtin_amdgcn_s_setprio(1);
            acc[0][0] = __builtin_amdgcn_mfma_f32_32x32x16_f16(a0, b_cur0, acc[0][0], 0, 0, 0);
            acc[1][0] = __builtin_amdgcn_mfma_f32_32x32x16_f16(a1, b_cur0, acc[1][0], 0, 0, 0);
            acc[0][1] = __builtin_amdgcn_mfma_f32_32x32x16_f16(a0, b_cur1, acc[0][1], 0, 0, 0);
            acc[1][1] = __builtin_amdgcn_mfma_f32_32x32x16_f16(a1, b_cur1, acc[1][1], 0, 0, 0);
            __builtin_amdgcn_s_setprio(0);
            b_cur0 = b_nx0; b_cur1 = b_nx1;
            b_nx0 = b_n20;  b_nx1 = b_n21;
        }
        if (c < 7) STAGE_CHUNK(AsB[(c + 1) & 1], p0, p1)
    }

    // ---- epilogue: softmax over N (bias already in acc) + direct store ----
    // C/D layout: col n = lane&31, row rr = (r&3) + 8*(r>>2) + 4*hf
#pragma unroll
    for (int ms = 0; ms < 2; ms++) {
#pragma unroll
        for (int r = 0; r < 16; r++) {
            float mx = fmaxf(acc[ms][0][r], acc[ms][1][r]);
#pragma unroll
            for (int off = 1; off < 32; off <<= 1) mx = fmaxf(mx, __shfl_xor(mx, off));
            if (l31 == r) red[wn][ms * 32 + (r & 3) + 8 * (r >> 2) + 4 * hf] = mx;
        }
    }
    __syncthreads();
    if (tid < 64) {
        float v = red[0][tid];
#pragma unroll
        for (int w = 1; w < 16; w++) v = fmaxf(v, red[w][tid]);
        redc[tid] = v;
    }
    __syncthreads();

#pragma unroll
    for (int ms = 0; ms < 2; ms++) {
#pragma unroll
        for (int r = 0; r < 16; r++) {
            const int rr = ms * 32 + (r & 3) + 8 * (r >> 2) + 4 * hf;
            const float rm = redc[rr];
            float s = 0.f;
#pragma unroll
            for (int nt = 0; nt < 2; nt++) {
                float e = __expf(acc[ms][nt][r] - rm);
                acc[ms][nt][r] = e;
                s += e;
            }
#pragma unroll
            for (int off = 1; off < 32; off <<= 1) s += __shfl_xor(s, off);
            if (l31 == r) red[wn][rr] = s;
        }
    }
    __syncthreads();
    if (tid < 64) {
        float v = 0.f;
#pragma unroll
        for (int w = 0; w < 16; w++) v += red[w][tid];
        redc[tid] = 1.0f / v;
    }
    __syncthreads();

#pragma unroll
    for (int ms = 0; ms < 2; ms++) {
        float invr[16];
#pragma unroll
        for (int r = 0; r < 16; r++)
            invr[r] = redc[ms * 32 + (r & 3) + 8 * (r >> 2) + 4 * hf];
#pragma unroll
        for (int nt = 0; nt < 2; nt++) {
            const int n = wn * 64 + nt * 32 + l31;
            float* op = out + ((size_t)b * Nd + n) * Ld + l0 + ms * 32 + hf * 4;
#pragma unroll
            for (int g = 0; g < 4; g++) {
                float4 v = make_float4(acc[ms][nt][g * 4 + 0] * invr[g * 4 + 0],
                                       acc[ms][nt][g * 4 + 1] * invr[g * 4 + 1],
                                       acc[ms][nt][g * 4 + 2] * invr[g * 4 + 2],
                                       acc[ms][nt][g * 4 + 3] * invr[g * 4 + 3]);
                *(float4*)(op + 8 * g) = v;
            }
        }
    }
}

// ---------------------------------------------------------------------------
// Workspace layout (2.1 MB + pad):
//   bias f32 [1024]        4 KB @ 0x0
//   Bh   f16 [1M + 2K pad] 2 MB + 4 KB @ 0x10000  (pad for 2-deep tail reads)
// ---------------------------------------------------------------------------
extern "C" void kernel_launch(void* const* d_in, const int* in_sizes, int n_in,
                              void* d_out, int out_size, void* d_ws, size_t ws_size,
                              hipStream_t stream) {
    (void)in_sizes; (void)n_in; (void)out_size; (void)ws_size;

    const float* F    = (const float*)d_in[0];   // (768, 512)
    const float* enc  = (const float*)d_in[1];   // (512, 32, 1024)
    const float* Wlin = (const float*)d_in[2];   // (512, 1024)
    const float* blin = (const float*)d_in[3];   // (512,)
    const float* Wfea = (const float*)d_in[4];   // (512, 1024)
    const float* bfea = (const float*)d_in[5];   // (512,)
    const float* V    = (const float*)d_in[6];   // (256, 512)
    float* out = (float*)d_out;                  // (32, 1024, 512)

    char* ws = (char*)d_ws;
    float*    bias = (float*)ws;                  // 4 KB
    _Float16* Bh   = (_Float16*)(ws + 0x10000);   // 2 MB (+4 KB pad)

    build_wpack<<<dim3(32, 32), 256, 0, stream>>>(F, Wfea, V, Wlin, Bh);
    build_bias<<<dim3(1024), 64, 0, stream>>>(F, bfea, V, blin, bias);
    gemm_direct<<<dim3(256), 1024, 0, stream>>>(enc, Bh, bias, out);
}